// Round 13
// baseline (107.303 us; speedup 1.0000x reference)
//
#include <hip/hip_runtime.h>

#define HDIM 8
#define CHUNK 8    // steps per LDS chunk (T=512 -> 64 chunks)

typedef float v4f __attribute__((ext_vector_type(4)));
typedef float v2f __attribute__((ext_vector_type(2)));

// ---- fast device math (v_exp_f32 / v_rcp_f32) ----
__device__ __forceinline__ float ex2(float x) {
#if __has_builtin(__builtin_amdgcn_exp2f)
    return __builtin_amdgcn_exp2f(x);
#else
    return exp2f(x);
#endif
}
__device__ __forceinline__ float rcp(float x) {
#if __has_builtin(__builtin_amdgcn_rcpf)
    return __builtin_amdgcn_rcpf(x);
#else
    return 1.0f / x;
#endif
}

// v_mov_b32_dpp row_ror:N (probe only)
#define DPP_ROR(v, N)                                                        \
    __int_as_float(__builtin_amdgcn_update_dpp(                              \
        0, __float_as_int(v), 0x120 + (N), 0xF, 0xF, true))

// ---- single-instruction asm helpers ----
#define ASM_FMA(d, a, b, c)                                                  \
    asm volatile("v_fma_f32 %0, %1, %2, %3"                                  \
                 : "=v"(d) : "v"(a), "v"(b), "v"(c))
#define ASM_MULD(d, h, w, ROT)                                               \
    asm volatile("v_mul_f32_dpp %0, %1, %2 row_ror:" #ROT                    \
                 " row_mask:0xf bank_mask:0xf"                               \
                 : "=v"(d) : "v"(h), "v"(w))
#define ASM_FMACD(d, h, w, ROT)                                              \
    asm volatile("v_fmac_f32_dpp %0, %1, %2 row_ror:" #ROT                   \
                 " row_mask:0xf bank_mask:0xf"                               \
                 : "+v"(d) : "v"(h), "v"(w))

#define KEEPALIVE16(a)                                                       \
    asm volatile("" : "+v"(a##0), "+v"(a##1), "+v"(a##2), "+v"(a##3),        \
                      "+v"(a##4), "+v"(a##5), "+v"(a##6), "+v"(a##7),        \
                      "+v"(a##8), "+v"(a##9), "+v"(a##10), "+v"(a##11),      \
                      "+v"(a##12), "+v"(a##13), "+v"(a##14), "+v"(a##15))
#define KEEPALIVE8(a)                                                        \
    asm volatile("" : "+v"(a##0), "+v"(a##1), "+v"(a##2), "+v"(a##3),        \
                      "+v"(a##4), "+v"(a##5), "+v"(a##6), "+v"(a##7))

// ---- TWO interleaved GRU steps (independent elements A and B, shared
// weights). Volatile-asm program order alternates A/B so B's ops fill A's
// stalls and vice versa. DPP-hazard: >=5 non-DPP ops sit between each hj
// write and the first DPP read of it. Math identical to round-11 (absmax
// 9.5e-7): blend hj' = s1 + rn*m2o, oz = Ez*z = exact 1-z.
__device__ __forceinline__ void gru_step2(
    float& hjA, float& hjB, v4f PA, v4f PB,
    const float (&wr)[8], const float (&wz)[8], const float (&wn)[8], float bhn)
{
    float raA, rbA, naA, nbA, zaA, zbA;
    float raB, rbB, naB, nbB, zaB, zbB;
    ASM_FMA (raA, wr[0], hjA, PA.x);  ASM_FMA (raB, wr[0], hjB, PB.x);
    ASM_FMA (naA, wn[0], hjA, bhn);   ASM_FMA (naB, wn[0], hjB, bhn);
    ASM_MULD(rbA, hjA, wr[4], 8);     ASM_MULD(rbB, hjB, wr[4], 8);
    ASM_MULD(nbA, hjA, wn[4], 8);     ASM_MULD(nbB, hjB, wn[4], 8);
    ASM_FMACD(raA, hjA, wr[1], 2);    ASM_FMACD(raB, hjB, wr[1], 2);
    ASM_FMACD(naA, hjA, wn[1], 2);    ASM_FMACD(naB, hjB, wn[1], 2);
    ASM_FMACD(rbA, hjA, wr[5], 10);   ASM_FMACD(rbB, hjB, wr[5], 10);
    ASM_FMACD(nbA, hjA, wn[5], 10);   ASM_FMACD(nbB, hjB, wn[5], 10);
    ASM_FMACD(raA, hjA, wr[2], 4);    ASM_FMACD(raB, hjB, wr[2], 4);
    ASM_FMACD(naA, hjA, wn[2], 4);    ASM_FMACD(naB, hjB, wn[2], 4);
    ASM_FMACD(rbA, hjA, wr[6], 12);   ASM_FMACD(rbB, hjB, wr[6], 12);
    ASM_FMACD(nbA, hjA, wn[6], 12);   ASM_FMACD(nbB, hjB, wn[6], 12);
    ASM_FMACD(raA, hjA, wr[3], 6);    ASM_FMACD(raB, hjB, wr[3], 6);
    ASM_FMACD(naA, hjA, wn[3], 6);    ASM_FMACD(naB, hjB, wn[3], 6);
    ASM_FMACD(rbA, hjA, wr[7], 14);   ASM_FMACD(rbB, hjB, wr[7], 14);
    ASM_FMACD(nbA, hjA, wn[7], 14);   ASM_FMACD(nbB, hjB, wn[7], 14);
    const float arA = raA + rbA,  arB = raB + rbB;
    const float ErA = ex2(arA),   ErB = ex2(arB);
    // z-gate dots: off critical path, fill the ex2 latency window
    ASM_FMA (zaA, wz[0], hjA, PA.y);  ASM_FMA (zaB, wz[0], hjB, PB.y);
    ASM_MULD(zbA, hjA, wz[4], 8);     ASM_MULD(zbB, hjB, wz[4], 8);
    ASM_FMACD(zaA, hjA, wz[1], 2);    ASM_FMACD(zaB, hjB, wz[1], 2);
    ASM_FMACD(zbA, hjA, wz[5], 10);   ASM_FMACD(zbB, hjB, wz[5], 10);
    ASM_FMACD(zaA, hjA, wz[2], 4);    ASM_FMACD(zaB, hjB, wz[2], 4);
    ASM_FMACD(zbA, hjA, wz[6], 12);   ASM_FMACD(zbB, hjB, wz[6], 12);
    ASM_FMACD(zaA, hjA, wz[3], 6);    ASM_FMACD(zaB, hjB, wz[3], 6);
    ASM_FMACD(zbA, hjA, wz[7], 14);   ASM_FMACD(zbB, hjB, wz[7], 14);
    const float anA = naA + nbA,      anB = naB + nbB;
    const float rA  = rcp(1.0f + ErA), rB = rcp(1.0f + ErB);
    const float azA = zaA + zbA,      azB = zaB + zbB;
    const float EzA = ex2(azA),       EzB = ex2(azB);
    const float uA  = fmaf(rA, anA, PA.z), uB = fmaf(rB, anB, PB.z);
    const float EnA = ex2(uA),        EnB = ex2(uB);
    const float zA  = rcp(1.0f + EzA), zB = rcp(1.0f + EzB);
    const float qA  = zA * hjA,       qB  = zB * hjB;
    const float ozA = EzA * zA,       ozB = EzB * zB;   // exact 1-z
    const float s1A = qA + ozA,       s1B = qB + ozB;
    const float m2oA = -2.0f * ozA,   m2oB = -2.0f * ozB;
    const float rnA = rcp(1.0f + EnA), rnB = rcp(1.0f + EnB);
    hjA = fmaf(rnA, m2oA, s1A);
    hjB = fmaf(rnB, m2oB, s1B);
}

// ---- producer: prescaled projections for one 8-step chunk, one element-set.
// 8 loads pinned up-front (one memory latency per set), then compute+store.
template <int IN, int STRIDE>
__device__ __forceinline__ void produce_chunk8(
    const float* __restrict__ xb, int t0,
    const float (&ur)[4], const float (&uz)[4], const float (&un)[4],
    float cr, float cz, float cn,
    float4* __restrict__ dst, int lane)
{
    const float* bp = xb + (size_t)t0 * STRIDE;
#define PLOAD4(i) v4f x##i = *reinterpret_cast<const v4f*>(bp + (i) * STRIDE);
#define PLOAD2(i) v2f x##i = *reinterpret_cast<const v2f*>(bp + (i) * STRIDE);
#define PSTORE(i)                                                            \
    {                                                                        \
        float a = cr, b = cz, c = cn;                                        \
        _Pragma("unroll")                                                    \
        for (int i2 = 0; i2 < IN; ++i2) {                                    \
            a = fmaf(ur[i2], x##i[i2], a);                                   \
            b = fmaf(uz[i2], x##i[i2], b);                                   \
            c = fmaf(un[i2], x##i[i2], c);                                   \
        }                                                                    \
        dst[(i) * 64 + lane] = make_float4(a, b, c, 0.0f);                   \
    }
    if constexpr (IN == 4) {
        PLOAD4(0) PLOAD4(1) PLOAD4(2) PLOAD4(3)
        PLOAD4(4) PLOAD4(5) PLOAD4(6) PLOAD4(7)
        KEEPALIVE8(x);
        PSTORE(0) PSTORE(1) PSTORE(2) PSTORE(3)
        PSTORE(4) PSTORE(5) PSTORE(6) PSTORE(7)
    } else {
        PLOAD2(0) PLOAD2(1) PLOAD2(2) PLOAD2(3)
        PLOAD2(4) PLOAD2(5) PLOAD2(6) PLOAD2(7)
        KEEPALIVE8(x);
        PSTORE(0) PSTORE(1) PSTORE(2) PSTORE(3)
        PSTORE(4) PSTORE(5) PSTORE(6) PSTORE(7)
    }
#undef PLOAD4
#undef PLOAD2
#undef PSTORE
}

// ---- consumer: 8 interleaved step-pairs; LDS read only in pinned preload.
// q0..q7 = set-A steps 0..7, q8..q15 = set-B steps 0..7.
__device__ __forceinline__ void consume_chunk8(
    float& hjA, float& hjB,
    const float4* __restrict__ srcA, const float4* __restrict__ srcB, int lane,
    const float (&wr)[8], const float (&wz)[8], const float (&wn)[8], float bhn)
{
    const v4f* sA = reinterpret_cast<const v4f*>(srcA);
    const v4f* sB = reinterpret_cast<const v4f*>(srcB);
#define CLA(i)    v4f q##i = sA[(i) * 64 + lane];
#define CLB(i, k) v4f q##i = sB[(k) * 64 + lane];
    CLA(0) CLA(1) CLA(2) CLA(3) CLA(4) CLA(5) CLA(6) CLA(7)
    CLB(8, 0) CLB(9, 1) CLB(10, 2) CLB(11, 3)
    CLB(12, 4) CLB(13, 5) CLB(14, 6) CLB(15, 7)
    KEEPALIVE16(q);   // 16 ds_read_b128 complete here; no LDS below
#undef CLA
#undef CLB
    gru_step2(hjA, hjB, q0, q8,  wr, wz, wn, bhn);
    gru_step2(hjA, hjB, q1, q9,  wr, wz, wn, bhn);
    gru_step2(hjA, hjB, q2, q10, wr, wz, wn, bhn);
    gru_step2(hjA, hjB, q3, q11, wr, wz, wn, bhn);
    gru_step2(hjA, hjB, q4, q12, wr, wz, wn, bhn);
    gru_step2(hjA, hjB, q5, q13, wr, wz, wn, bhn);
    gru_step2(hjA, hjB, q6, q14, wr, wz, wn, bhn);
    gru_step2(hjA, hjB, q7, q15, wr, wz, wn, bhn);
}

// block = 256 threads = 4 waves; 16 batch elements per block (sets A,B).
//   wave 0: consumer bbox (A+B)   wave 1: consumer flow (A+B)
//   wave 2: producer bbox (A+B)   wave 3: producer flow (A+B)
// Lane mapping: el = ((lane>>4)<<1)|(lane&1) in 0..7, unit j = (lane&15)>>1.
// Set A = elements base+el, set B = base+8+el.
__global__ __launch_bounds__(256, 1)
void gru_fused_kernel(const float* __restrict__ bbox, const float* __restrict__ flow,
                      const float* __restrict__ Wih_b, const float* __restrict__ Whh_b,
                      const float* __restrict__ bih_b, const float* __restrict__ bhh_b,
                      const float* __restrict__ Wih_f, const float* __restrict__ Whh_f,
                      const float* __restrict__ bih_f, const float* __restrict__ bhh_f,
                      float* __restrict__ out, int T)
{
    const float NL2E = -1.4426950408889634f;  // -log2(e)
    const float L2E2 =  2.8853900817779268f;  //  2*log2(e)

    __shared__ float4 projLDS[2][2][2][CHUNK * 64];  // [buf][gru][set]: 64KiB
    __shared__ float sh[2][16][HDIM];

    const int tid  = threadIdx.x;
    const int wave = tid >> 6;
    const int lane = tid & 63;
    const int gru  = wave & 1;            // 0 = bbox, 1 = flow
    const bool is_cons = (wave < 2);
    const int NC = T / CHUNK;             // 64

    const int eloc = ((lane >> 4) << 1) | (lane & 1);   // element 0..7
    const int j    = (lane & 15) >> 1;                  // hidden unit 0..7
    const int eA   = blockIdx.x * 16 + eloc;            // set-A element
    const int eB   = eA + 8;                            // set-B element

    // ---- consumer state ----
    float wr[8], wz[8], wn[8];
    float bhn = 0.0f;
    // ---- producer state ----
    float ur[4] = {0, 0, 0, 0}, uz[4] = {0, 0, 0, 0}, un[4] = {0, 0, 0, 0};
    float cr = 0.0f, cz = 0.0f, cn = 0.0f;
    const float* pxA = nullptr;
    const float* pxB = nullptr;

    if (is_cons) {
        const float* Whh = gru ? Whh_f : Whh_b;
        const float* bhh = gru ? bhh_f : bhh_b;
        // probe row_ror direction: partner of rotation 2 holds unit (j +- 1)&7
        float nbp = DPP_ROR((float)j, 2);
        const int dstep = (nbp == (float)((j + 1) & 7)) ? 1 : 7;
#pragma unroll
        for (int m = 0; m < 8; ++m) {
            const int k = (j + dstep * m) & 7;
            wr[m] = NL2E * Whh[(j     ) * HDIM + k];
            wz[m] = NL2E * Whh[(j +  8) * HDIM + k];
            wn[m] = L2E2 * Whh[(j + 16) * HDIM + k];
        }
        bhn = L2E2 * bhh[j + 16];
    } else {
        const float* Wih = gru ? Wih_f : Wih_b;
        const float* bih = gru ? bih_f : bih_b;
        const float* bhh = gru ? bhh_f : bhh_b;
        const int IN = gru ? 2 : 4;
        pxA = gru ? (flow + (size_t)eA * T * 50 + 24)
                  : (bbox + (size_t)eA * T * 4);
        pxB = gru ? (flow + (size_t)eB * T * 50 + 24)
                  : (bbox + (size_t)eB * T * 4);
        for (int i = 0; i < IN; ++i) {
            ur[i] = NL2E * Wih[(j     ) * IN + i];
            uz[i] = NL2E * Wih[(j +  8) * IN + i];
            un[i] = L2E2 * Wih[(j + 16) * IN + i];
        }
        cr = NL2E * (bih[j]     + bhh[j]);
        cz = NL2E * (bih[j + 8] + bhh[j + 8]);
        cn = L2E2 * bih[j + 16];
    }

    float hjA = 0.0f, hjB = 0.0f;

    // prologue: produce chunk 0 (both sets) into buffer 0
    if (!is_cons) {
        float4* dA = &projLDS[0][gru][0][0];
        float4* dB = &projLDS[0][gru][1][0];
        if (gru == 0) {
            produce_chunk8<4, 4 >(pxA, 0, ur, uz, un, cr, cz, cn, dA, lane);
            produce_chunk8<4, 4 >(pxB, 0, ur, uz, un, cr, cz, cn, dB, lane);
        } else {
            produce_chunk8<2, 50>(pxA, 0, ur, uz, un, cr, cz, cn, dA, lane);
            produce_chunk8<2, 50>(pxB, 0, ur, uz, un, cr, cz, cn, dB, lane);
        }
    }
    __syncthreads();

    for (int c = 0; c < NC; ++c) {
        if (is_cons) {
            consume_chunk8(hjA, hjB,
                           &projLDS[c & 1][gru][0][0], &projLDS[c & 1][gru][1][0],
                           lane, wr, wz, wn, bhn);
        } else if (c + 1 < NC) {
            float4* dA = &projLDS[(c + 1) & 1][gru][0][0];
            float4* dB = &projLDS[(c + 1) & 1][gru][1][0];
            const int t0 = (c + 1) * CHUNK;
            if (gru == 0) {
                produce_chunk8<4, 4 >(pxA, t0, ur, uz, un, cr, cz, cn, dA, lane);
                produce_chunk8<4, 4 >(pxB, t0, ur, uz, un, cr, cz, cn, dB, lane);
            } else {
                produce_chunk8<2, 50>(pxA, t0, ur, uz, un, cr, cz, cn, dA, lane);
                produce_chunk8<2, 50>(pxB, t0, ur, uz, un, cr, cz, cn, dB, lane);
            }
        }
        __syncthreads();
    }

    if (is_cons) {
        sh[gru][eloc][j]     = hjA;
        sh[gru][eloc + 8][j] = hjB;
    }
    __syncthreads();
    if (wave == 0) {
        out[(size_t)eA * HDIM + j] = 0.5f * (sh[0][eloc][j]     + sh[1][eloc][j]);
        out[(size_t)eB * HDIM + j] = 0.5f * (sh[0][eloc + 8][j] + sh[1][eloc + 8][j]);
    }
}

extern "C" void kernel_launch(void* const* d_in, const int* in_sizes, int n_in,
                              void* d_out, int out_size, void* d_ws, size_t ws_size,
                              hipStream_t stream) {
    const float* bbox  = (const float*)d_in[0];
    const float* flow  = (const float*)d_in[1];
    const float* Wih_b = (const float*)d_in[2];
    const float* Whh_b = (const float*)d_in[3];
    const float* bih_b = (const float*)d_in[4];
    const float* bhh_b = (const float*)d_in[5];
    const float* Wih_f = (const float*)d_in[6];
    const float* Whh_f = (const float*)d_in[7];
    const float* bih_f = (const float*)d_in[8];
    const float* bhh_f = (const float*)d_in[9];
    float* out = (float*)d_out;

    const int B = out_size / HDIM;            // 1024
    const int T = in_sizes[0] / (4 * B);      // 512

    dim3 grid(B / 16), block(256);
    gru_fused_kernel<<<grid, block, 0, stream>>>(
        bbox, flow, Wih_b, Whh_b, bih_b, bhh_b,
        Wih_f, Whh_f, bih_f, bhh_f, out, T);
}

// Round 14
// 56.820 us; speedup vs baseline: 1.8885x; 1.8885x over previous
//
#include <hip/hip_runtime.h>

#define HDIM 8
#define CHUNK 16   // steps per LDS chunk (T=512 -> 32 chunks)

typedef float v4f __attribute__((ext_vector_type(4)));
typedef float v2f __attribute__((ext_vector_type(2)));

// ---- fast device math (v_exp_f32 / v_rcp_f32) ----
__device__ __forceinline__ float ex2(float x) {
#if __has_builtin(__builtin_amdgcn_exp2f)
    return __builtin_amdgcn_exp2f(x);
#else
    return exp2f(x);
#endif
}
__device__ __forceinline__ float rcp(float x) {
#if __has_builtin(__builtin_amdgcn_rcpf)
    return __builtin_amdgcn_rcpf(x);
#else
    return 1.0f / x;
#endif
}

// v_mov_b32_dpp row_ror:N (N immediate). 0x120+N = ROW_ROR DPP ctrl.
#define DPP_ROR(v, N)                                                        \
    __int_as_float(__builtin_amdgcn_update_dpp(                              \
        0, __float_as_int(v), 0x120 + (N), 0xF, 0xF, true))

// Lane mapping (producer and consumer identical):
//   row = lane>>4 (16-lane DPP row), p = lane&15
//   element el = (row<<1)|(p&1), hidden unit j = p>>1
// LDS layout: slot [s*64 + lane] (float4) — wave accesses are 64 contiguous
// 16B slots => conflict-free.

// Keep-alive: forces all 16 named vector values to be materialized in VGPRs
// at this program point (=> the loads feeding them are complete; one combined
// compiler-inserted waitcnt instead of 16 per-use waits).
#define KEEPALIVE16(a)                                                       \
    asm volatile("" : "+v"(a##0), "+v"(a##1), "+v"(a##2), "+v"(a##3),        \
                      "+v"(a##4), "+v"(a##5), "+v"(a##6), "+v"(a##7),        \
                      "+v"(a##8), "+v"(a##9), "+v"(a##10), "+v"(a##11),      \
                      "+v"(a##12), "+v"(a##13), "+v"(a##14), "+v"(a##15))

// ---- producer: prescaled input projections for one 16-step chunk ----
// All 16 x-loads issued up-front and pinned via keep-alive (one HBM latency
// per chunk), then 16 projection computes + conflict-free LDS writes.
template <int IN, int STRIDE>
__device__ __forceinline__ void produce_chunk(
    const float* __restrict__ xb, int t0,
    const float (&ur)[4], const float (&uz)[4], const float (&un)[4],
    float cr, float cz, float cn,
    float4* __restrict__ dst, int lane)
{
    const float* bp = xb + (size_t)t0 * STRIDE;
#define PLOAD4(i) v4f x##i = *reinterpret_cast<const v4f*>(bp + (i) * STRIDE);
#define PLOAD2(i) v2f x##i = *reinterpret_cast<const v2f*>(bp + (i) * STRIDE);
#define PSTORE(i)                                                            \
    {                                                                        \
        float a = cr, b = cz, c = cn;                                        \
        _Pragma("unroll")                                                    \
        for (int i2 = 0; i2 < IN; ++i2) {                                    \
            a = fmaf(ur[i2], x##i[i2], a);                                   \
            b = fmaf(uz[i2], x##i[i2], b);                                   \
            c = fmaf(un[i2], x##i[i2], c);                                   \
        }                                                                    \
        dst[(i) * 64 + lane] = make_float4(a, b, c, 0.0f);                   \
    }
    if constexpr (IN == 4) {
        PLOAD4(0) PLOAD4(1) PLOAD4(2) PLOAD4(3) PLOAD4(4) PLOAD4(5)
        PLOAD4(6) PLOAD4(7) PLOAD4(8) PLOAD4(9) PLOAD4(10) PLOAD4(11)
        PLOAD4(12) PLOAD4(13) PLOAD4(14) PLOAD4(15)
        KEEPALIVE16(x);
        PSTORE(0) PSTORE(1) PSTORE(2) PSTORE(3) PSTORE(4) PSTORE(5)
        PSTORE(6) PSTORE(7) PSTORE(8) PSTORE(9) PSTORE(10) PSTORE(11)
        PSTORE(12) PSTORE(13) PSTORE(14) PSTORE(15)
    } else {
        PLOAD2(0) PLOAD2(1) PLOAD2(2) PLOAD2(3) PLOAD2(4) PLOAD2(5)
        PLOAD2(6) PLOAD2(7) PLOAD2(8) PLOAD2(9) PLOAD2(10) PLOAD2(11)
        PLOAD2(12) PLOAD2(13) PLOAD2(14) PLOAD2(15)
        KEEPALIVE16(x);
        PSTORE(0) PSTORE(1) PSTORE(2) PSTORE(3) PSTORE(4) PSTORE(5)
        PSTORE(6) PSTORE(7) PSTORE(8) PSTORE(9) PSTORE(10) PSTORE(11)
        PSTORE(12) PSTORE(13) PSTORE(14) PSTORE(15)
    }
#undef PLOAD4
#undef PLOAD2
#undef PSTORE
}

// ---- consumer: 16 recurrence steps; LDS read ONLY in the pinned preload ----
// Recurrent matvec: 3 init FMAs (m=0) + 21 fused v_fmac_f32_dpp (m=1..7 for
// r,z,n) — the h all-gather is folded into the FMA issue slots. Three
// accumulator chains interleaved => FMA latency hidden.
__device__ __forceinline__ float consume_chunk(
    float hj, const float4* __restrict__ src, int lane,
    const float (&wr)[8], const float (&wz)[8], const float (&wn)[8], float bhn)
{
    const v4f* sp = reinterpret_cast<const v4f*>(src);
#define CLOAD(i) v4f p##i = sp[(i) * 64 + lane];
    CLOAD(0) CLOAD(1) CLOAD(2) CLOAD(3) CLOAD(4) CLOAD(5) CLOAD(6) CLOAD(7)
    CLOAD(8) CLOAD(9) CLOAD(10) CLOAD(11) CLOAD(12) CLOAD(13) CLOAD(14) CLOAD(15)
    KEEPALIVE16(p);   // 16 ds_read_b128 complete here; no LDS below
#undef CLOAD

#define FMAC3(ROT, M)                                                        \
    "v_fmac_f32_dpp %[ar], %[h], %[wr" #M "] row_ror:" #ROT                  \
    " row_mask:0xf bank_mask:0xf\n\t"                                        \
    "v_fmac_f32_dpp %[az], %[h], %[wz" #M "] row_ror:" #ROT                  \
    " row_mask:0xf bank_mask:0xf\n\t"                                        \
    "v_fmac_f32_dpp %[an], %[h], %[wn" #M "] row_ror:" #ROT                  \
    " row_mask:0xf bank_mask:0xf\n\t"

#define STEP(P)                                                              \
    {                                                                        \
        float ar = fmaf(wr[0], hj, (P).x);                                   \
        float az = fmaf(wz[0], hj, (P).y);                                   \
        float an_ = fmaf(wn[0], hj, bhn);                                    \
        asm volatile(                                                        \
            FMAC3(2, 1) FMAC3(4, 2) FMAC3(6, 3) FMAC3(8, 4)                  \
            FMAC3(10, 5) FMAC3(12, 6) FMAC3(14, 7)                           \
            : [ar] "+v"(ar), [az] "+v"(az), [an] "+v"(an_)                   \
            : [h] "v"(hj),                                                   \
              [wr1] "v"(wr[1]), [wz1] "v"(wz[1]), [wn1] "v"(wn[1]),          \
              [wr2] "v"(wr[2]), [wz2] "v"(wz[2]), [wn2] "v"(wn[2]),          \
              [wr3] "v"(wr[3]), [wz3] "v"(wz[3]), [wn3] "v"(wn[3]),          \
              [wr4] "v"(wr[4]), [wz4] "v"(wz[4]), [wn4] "v"(wn[4]),          \
              [wr5] "v"(wr[5]), [wz5] "v"(wz[5]), [wn5] "v"(wn[5]),          \
              [wr6] "v"(wr[6]), [wz6] "v"(wz[6]), [wn6] "v"(wn[6]),          \
              [wr7] "v"(wr[7]), [wz7] "v"(wz[7]), [wn7] "v"(wn[7]));         \
        float r = rcp(1.0f + ex2(ar));                                       \
        float z = rcp(1.0f + ex2(az));                                       \
        float u = fmaf(r, an_, (P).z);                                       \
        float n = fmaf(-2.0f, rcp(1.0f + ex2(u)), 1.0f);                     \
        hj = fmaf(z, hj - n, n);                                             \
    }
    STEP(p0) STEP(p1) STEP(p2) STEP(p3) STEP(p4) STEP(p5) STEP(p6) STEP(p7)
    STEP(p8) STEP(p9) STEP(p10) STEP(p11) STEP(p12) STEP(p13) STEP(p14) STEP(p15)
#undef STEP
#undef FMAC3
    return hj;
}

// block = 256 threads = 4 waves.
//   wave 0: consumer bbox   wave 1: consumer flow
//   wave 2: producer bbox   wave 3: producer flow
__global__ __launch_bounds__(256, 1)
void gru_fused_kernel(const float* __restrict__ bbox, const float* __restrict__ flow,
                      const float* __restrict__ Wih_b, const float* __restrict__ Whh_b,
                      const float* __restrict__ bih_b, const float* __restrict__ bhh_b,
                      const float* __restrict__ Wih_f, const float* __restrict__ Whh_f,
                      const float* __restrict__ bih_f, const float* __restrict__ bhh_f,
                      float* __restrict__ out, int T)
{
    const float NL2E = -1.4426950408889634f;  // -log2(e)
    const float L2E2 =  2.8853900817779268f;  //  2*log2(e)

    __shared__ float4 projLDS[2][2][CHUNK * 64];    // 64 KiB, lane-linear slots
    __shared__ float sh[2][8][HDIM];

    const int tid  = threadIdx.x;
    const int wave = tid >> 6;
    const int lane = tid & 63;
    const int gru  = wave & 1;            // 0 = bbox, 1 = flow
    const bool is_cons = (wave < 2);
    const int NC = T / CHUNK;             // 32

    const int eloc = ((lane >> 4) << 1) | (lane & 1);   // element 0..7
    const int j    = (lane & 15) >> 1;                  // hidden unit 0..7

    float wr[8], wz[8], wn[8];
    float bhn = 0.0f;
    float ur[4] = {0, 0, 0, 0}, uz[4] = {0, 0, 0, 0}, un[4] = {0, 0, 0, 0};
    float cr = 0.0f, cz = 0.0f, cn = 0.0f;
    const float* pxb = nullptr;

    if (is_cons) {
        const float* Whh = gru ? Whh_f : Whh_b;
        const float* bhh = gru ? bhh_f : bhh_b;
        // probe row_ror direction: partner of rotation 2 holds unit (j +- 1)&7
        float nbp = DPP_ROR((float)j, 2);
        const int dstep = (nbp == (float)((j + 1) & 7)) ? 1 : 7;
#pragma unroll
        for (int m = 0; m < 8; ++m) {
            const int k = (j + dstep * m) & 7;
            wr[m] = NL2E * Whh[(j     ) * HDIM + k];
            wz[m] = NL2E * Whh[(j +  8) * HDIM + k];
            wn[m] = L2E2 * Whh[(j + 16) * HDIM + k];
        }
        bhn = L2E2 * bhh[j + 16];
    } else {
        const float* Wih = gru ? Wih_f : Wih_b;
        const float* bih = gru ? bih_f : bih_b;
        const float* bhh = gru ? bhh_f : bhh_b;
        const int IN = gru ? 2 : 4;
        const int pe = blockIdx.x * 8 + eloc;
        pxb = gru ? (flow + (size_t)pe * T * 50 + 24)
                  : (bbox + (size_t)pe * T * 4);
        for (int i = 0; i < IN; ++i) {
            ur[i] = NL2E * Wih[(j     ) * IN + i];
            uz[i] = NL2E * Wih[(j +  8) * IN + i];
            un[i] = L2E2 * Wih[(j + 16) * IN + i];
        }
        cr = NL2E * (bih[j]     + bhh[j]);
        cz = NL2E * (bih[j + 8] + bhh[j + 8]);
        cn = L2E2 * bih[j + 16];
    }

    float hj = 0.0f;

    // prologue: produce chunk 0 into buffer 0
    if (!is_cons) {
        float4* dst = projLDS[0][gru];
        if (gru == 0) produce_chunk<4, 4 >(pxb, 0, ur, uz, un, cr, cz, cn, dst, lane);
        else          produce_chunk<2, 50>(pxb, 0, ur, uz, un, cr, cz, cn, dst, lane);
    }
    __syncthreads();

    for (int c = 0; c < NC; ++c) {
        if (is_cons) {
            hj = consume_chunk(hj, projLDS[c & 1][gru], lane, wr, wz, wn, bhn);
        } else if (c + 1 < NC) {
            float4* dst = projLDS[(c + 1) & 1][gru];
            if (gru == 0) produce_chunk<4, 4 >(pxb, (c + 1) * CHUNK, ur, uz, un, cr, cz, cn, dst, lane);
            else          produce_chunk<2, 50>(pxb, (c + 1) * CHUNK, ur, uz, un, cr, cz, cn, dst, lane);
        }
        __syncthreads();
    }

    if (is_cons) sh[gru][eloc][j] = hj;
    __syncthreads();
    if (wave == 0) {
        const int e = blockIdx.x * 8 + eloc;
        out[(size_t)e * HDIM + j] = 0.5f * (sh[0][eloc][j] + sh[1][eloc][j]);
    }
}

extern "C" void kernel_launch(void* const* d_in, const int* in_sizes, int n_in,
                              void* d_out, int out_size, void* d_ws, size_t ws_size,
                              hipStream_t stream) {
    const float* bbox  = (const float*)d_in[0];
    const float* flow  = (const float*)d_in[1];
    const float* Wih_b = (const float*)d_in[2];
    const float* Whh_b = (const float*)d_in[3];
    const float* bih_b = (const float*)d_in[4];
    const float* bhh_b = (const float*)d_in[5];
    const float* Wih_f = (const float*)d_in[6];
    const float* Whh_f = (const float*)d_in[7];
    const float* bih_f = (const float*)d_in[8];
    const float* bhh_f = (const float*)d_in[9];
    float* out = (float*)d_out;

    const int B = out_size / HDIM;            // 1024
    const int T = in_sizes[0] / (4 * B);      // 512

    dim3 grid(B / 8), block(256);
    gru_fused_kernel<<<grid, block, 0, stream>>>(
        bbox, flow, Wih_b, Whh_b, bih_b, bhh_b,
        Wih_f, Whh_f, bih_f, bhh_f, out, T);
}